// Round 5
// baseline (182.632 us; speedup 1.0000x reference)
//
#include <hip/hip_runtime.h>

#define BB 4
#define SS 1024
#define DD 1024
#define HH 16
#define DKK 64
#define MM (BB*SS)   // 4096

typedef __bf16 bf16;
typedef __bf16 bf16x8 __attribute__((ext_vector_type(8)));
typedef float f32x4 __attribute__((ext_vector_type(4)));

__device__ __forceinline__ f32x4 mfma16(bf16x8 a, bf16x8 b, f32x4 c) {
  return __builtin_amdgcn_mfma_f32_16x16x32_bf16(a, b, c, 0, 0, 0);
}

__device__ __forceinline__ float fexp2(float x) {
  return __builtin_amdgcn_exp2f(x);
}

// ---------------- mask -> bitmask ----------------
__global__ __launch_bounds__(256) void k_mask_bits(const int* __restrict__ mask,
                                                   unsigned* __restrict__ bits) {
  const int row = blockIdx.x;
  const int tid = threadIdx.x;
  const int lane = tid & 63, wv = tid >> 6;
#pragma unroll
  for (int it = 0; it < 4; ++it) {
    const int base = it * 256 + wv * 64;
    const int col = base + lane;
    unsigned long long bal = __ballot(mask[(size_t)row * SS + col] != 0);
    if (lane == 0) {
      bits[(size_t)row * 32 + (base >> 5)] = (unsigned)bal;
      bits[(size_t)row * 32 + (base >> 5) + 1] = (unsigned)(bal >> 32);
    }
  }
}

// ---------------- GEMM  C = (A @ W^T) * oscale ----------------
template<int AF32, int CF32>
__device__ __forceinline__ void gemm_body(const void* __restrict__ Ap,
                                          const float* __restrict__ Wp,
                                          void* __restrict__ Cp,
                                          int Mtot, int N, int K, int blk,
                                          float oscale) {
  __shared__ bf16 Al[128 * 40];
  __shared__ bf16 Bl[128 * 40];
  const int tid = threadIdx.x;
  const int lane = tid & 63;
  const int l15 = lane & 15, l4 = lane >> 4;
  const int wv = tid >> 6;
  const int nbm = Mtot >> 7;
  const int bm = blk % nbm, bn = blk / nbm;
  const size_t m0 = (size_t)bm << 7, n0 = (size_t)bn << 7;
  const int wr = (wv >> 1) << 6, wc = (wv & 1) << 6;
  const int srow = tid >> 2, scol = (tid & 3) << 3;

  f32x4 acc[4][4];
#pragma unroll
  for (int i = 0; i < 4; ++i)
#pragma unroll
    for (int j = 0; j < 4; ++j) acc[i][j] = f32x4{0.f, 0.f, 0.f, 0.f};

  for (int k0 = 0; k0 < K; k0 += 32) {
#pragma unroll
    for (int c = 0; c < 2; ++c) {
      const int row = (c << 6) + srow;
      bf16x8 av;
      if (AF32) {
        const float* s = (const float*)Ap + (m0 + row) * (size_t)K + k0 + scol;
        f32x4 v0 = *(const f32x4*)s;
        f32x4 v1 = *(const f32x4*)(s + 4);
#pragma unroll
        for (int j = 0; j < 4; ++j) { av[j] = (bf16)v0[j]; av[4 + j] = (bf16)v1[j]; }
      } else {
        av = *(const bf16x8*)((const bf16*)Ap + (m0 + row) * (size_t)K + k0 + scol);
      }
      *(bf16x8*)&Al[row * 40 + scol] = av;

      const float* ws_ = Wp + (n0 + row) * (size_t)K + k0 + scol;
      f32x4 w0 = *(const f32x4*)ws_;
      f32x4 w1 = *(const f32x4*)(ws_ + 4);
      bf16x8 wv8;
#pragma unroll
      for (int j = 0; j < 4; ++j) { wv8[j] = (bf16)w0[j]; wv8[4 + j] = (bf16)w1[j]; }
      *(bf16x8*)&Bl[row * 40 + scol] = wv8;
    }
    __syncthreads();

    bf16x8 af[4], bfv[4];
#pragma unroll
    for (int t = 0; t < 4; ++t) {
      af[t]  = *(const bf16x8*)&Al[(wr + t * 16 + l15) * 40 + l4 * 8];
      bfv[t] = *(const bf16x8*)&Bl[(wc + t * 16 + l15) * 40 + l4 * 8];
    }
    __builtin_amdgcn_s_setprio(1);
#pragma unroll
    for (int mt = 0; mt < 4; ++mt)
#pragma unroll
      for (int nt = 0; nt < 4; ++nt)
        acc[mt][nt] = mfma16(af[mt], bfv[nt], acc[mt][nt]);
    __builtin_amdgcn_s_setprio(0);
    __syncthreads();
  }

#pragma unroll
  for (int mt = 0; mt < 4; ++mt)
#pragma unroll
    for (int nt = 0; nt < 4; ++nt)
#pragma unroll
      for (int r = 0; r < 4; ++r) {
        const size_t row = m0 + wr + mt * 16 + l4 * 4 + r;
        const size_t col = n0 + wc + nt * 16 + l15;
        if (CF32) ((float*)Cp)[row * N + col] = acc[mt][nt][r];
        else      ((bf16*)Cp)[row * N + col] = (bf16)(acc[mt][nt][r] * oscale);
      }
}

// Q is pre-scaled by 1/sqrt(dk) * log2(e) so attention works in exp2 domain.
#define QSCALE 0.1803368801111204f

__global__ __launch_bounds__(256)
void k_gemm_qkv(const float* __restrict__ A0, const float* __restrict__ A1,
                const float* __restrict__ A2, const float* __restrict__ W0,
                const float* __restrict__ W1, const float* __restrict__ W2,
                bf16* __restrict__ C0, bf16* __restrict__ C1, bf16* __restrict__ C2) {
  const int z = blockIdx.z;
  const float* A = (z == 0) ? A0 : (z == 1) ? A1 : A2;
  const float* W = (z == 0) ? W0 : (z == 1) ? W1 : W2;
  bf16* C = (z == 0) ? C0 : (z == 1) ? C1 : C2;
  const float sc = (z == 0) ? QSCALE : 1.0f;
  gemm_body<1, 0>(A, W, C, MM, DD, DD, blockIdx.x, sc);
}

__global__ __launch_bounds__(256)
void k_gemm_out(const bf16* __restrict__ A, const float* __restrict__ W,
                float* __restrict__ C) {
  gemm_body<0, 1>(A, W, C, MM, DD, DD, blockIdx.x, 1.0f);
}

// ---------------- flash attention, split-kv across waves ----------------
// Block = 64 q rows x full S. Each wave owns a disjoint kv quarter (256) and
// ALL 64 q (4 qtiles), KVBLK=32 per iter, 8 iters, NO barriers in main loop
// (per-wave private V^T tile in own LDS slice). Final: LDS merge of the 4
// partial (O, m, l) states (deterministic serialized rounds).
#define VKS 34
__global__ __launch_bounds__(256, 3)
void k_attn(const bf16* __restrict__ Qw, const bf16* __restrict__ Kw,
            const bf16* __restrict__ Vw, const unsigned* __restrict__ mb,
            bf16* __restrict__ Xw) {
  __shared__ union {
    bf16 v[4][64 * VKS];                       // per-wave V^T [d][k], 17408 B
    struct { float o[64 * 68]; float ml[4][2][64]; } m;  // 19456 B
  } sh;
  const int tid = threadIdx.x, lane = tid & 63, w = tid >> 6;
  const int l15 = lane & 15, g = lane >> 4, gq4 = g << 2;
  const unsigned bid = blockIdx.x;
  // XCD swizzle: all 16 q-blocks of one (b,h) land on one XCD
  const int bh = ((bid & 7) << 3) + (bid >> 7);
  const int qt_blk = (bid >> 3) & 15;
  const int h = bh & 15, b = bh >> 4;
  const int q0 = qt_blk * 64;

  // Q fragments (B operand): Q[q0 + qt*16 + l15][g*8 + j (+32)]
  bf16x8 qf[4][2];
  {
    const bf16* Qb = Qw + (size_t)(b * SS + q0 + l15) * DD + h * 64 + g * 8;
#pragma unroll
    for (int qt = 0; qt < 4; ++qt) {
      qf[qt][0] = *(const bf16x8*)(Qb + (size_t)qt * 16 * DD);
      qf[qt][1] = *(const bf16x8*)(Qb + (size_t)qt * 16 * DD + 32);
    }
  }
  const bf16* Kb = Kw + (size_t)(b * SS) * DD + h * 64 + g * 8;
  const bf16* Vbp = Vw + (size_t)(b * SS) * DD + h * 64 + l15 * 4;
  const unsigned* mbase = mb + (size_t)(b * SS + q0 + l15) * 32;

  f32x4 acco[4][4];  // [qt][dt]: O[q = qt*16+g*4+r][d = dt*16+l15]
#pragma unroll
  for (int qt = 0; qt < 4; ++qt)
#pragma unroll
    for (int dt = 0; dt < 4; ++dt) acco[qt][dt] = f32x4{0.f, 0.f, 0.f, 0.f};
  float mx[4], ssum[4];
#pragma unroll
  for (int qt = 0; qt < 4; ++qt) { mx[qt] = -3e38f; ssum[qt] = 0.f; }

  bf16* Vl = sh.v[w];
  const int idxA = (l15 + ((g & 1) << 5)) << 2;
  const int idxB = idxA + 64;
  const int kvw = w << 8;                      // wave's kv range base

  for (int it = 0; it < 8; ++it) {
    const int kv0 = kvw + it * 32;
    // V global loads: lane (l15,g) rows kv0+4i+g, d-chunk l15*4 (coalesced)
    union { uint2 u; bf16 h4[4]; } vld[8];
#pragma unroll
    for (int i = 0; i < 8; ++i)
      vld[i].u = *(const uint2*)(Vbp + (size_t)(kv0 + i * 4 + g) * DD);
    // K fragments (A operand)
    bf16x8 kf[2][2];
#pragma unroll
    for (int st = 0; st < 2; ++st) {
      const bf16* kp = Kb + (size_t)(kv0 + st * 16 + l15) * DD;
      kf[st][0] = *(const bf16x8*)kp;
      kf[st][1] = *(const bf16x8*)(kp + 32);
    }
    // mask words (one 32-bit word covers this KVBLK)
    unsigned mwd[4];
#pragma unroll
    for (int qt = 0; qt < 4; ++qt)
      mwd[qt] = mbase[(size_t)(qt * 16) * 32 + (kv0 >> 5)];
    // stage V^T into private LDS slice: Vl[d][k], d = 4*l15+j, k = 4i+g
#pragma unroll
    for (int i = 0; i < 8; ++i)
#pragma unroll
      for (int j = 0; j < 4; ++j)
        Vl[(l15 * 4 + j) * VKS + i * 4 + g] = vld[i].h4[j];
    // V fragments (B operand): within-wave RAW on LDS, hw-ordered
    bf16x8 vb[4];
#pragma unroll
    for (int dt = 0; dt < 4; ++dt)
      vb[dt] = *(const bf16x8*)&Vl[(dt * 16 + l15) * VKS + g * 8];

#pragma unroll
    for (int qt = 0; qt < 4; ++qt) {
      // swapped QK^T: lane (l15,g) -> S[k = st*16+g*4+r][q = qt*16+l15]
      f32x4 s0 = f32x4{0.f, 0.f, 0.f, 0.f}, s1 = f32x4{0.f, 0.f, 0.f, 0.f};
      s0 = mfma16(kf[0][0], qf[qt][0], s0);
      s0 = mfma16(kf[0][1], qf[qt][1], s0);
      s1 = mfma16(kf[1][0], qf[qt][0], s1);
      s1 = mfma16(kf[1][1], qf[qt][1], s1);
      float p[2][4];
#pragma unroll
      for (int r = 0; r < 4; ++r) {
        p[0][r] = ((mwd[qt] >> (gq4 + r)) & 1) ? s0[r] : -1e9f;
        p[1][r] = ((mwd[qt] >> (16 + gq4 + r)) & 1) ? s1[r] : -1e9f;
      }
      float rm = fmaxf(fmaxf(fmaxf(p[0][0], p[0][1]), fmaxf(p[0][2], p[0][3])),
                       fmaxf(fmaxf(p[1][0], p[1][1]), fmaxf(p[1][2], p[1][3])));
      rm = fmaxf(rm, __shfl_xor(rm, 16));
      rm = fmaxf(rm, __shfl_xor(rm, 32));
      // defer-max: rescale only when max grew by > 8
      if (!__all(rm <= mx[qt] + 8.0f)) {
        const float mn = fmaxf(mx[qt], rm);
        const float scal = fexp2(mx[qt] - mn);
        mx[qt] = mn;
        ssum[qt] *= scal;
        const float s0f = __shfl(scal, gq4);
        const float s1f = __shfl(scal, gq4 + 1);
        const float s2f = __shfl(scal, gq4 + 2);
        const float s3f = __shfl(scal, gq4 + 3);
#pragma unroll
        for (int dt = 0; dt < 4; ++dt) {
          acco[qt][dt][0] *= s0f; acco[qt][dt][1] *= s1f;
          acco[qt][dt][2] *= s2f; acco[qt][dt][3] *= s3f;
        }
      }
#pragma unroll
      for (int st = 0; st < 2; ++st)
#pragma unroll
        for (int r = 0; r < 4; ++r) {
          p[st][r] = fexp2(p[st][r] - mx[qt]);
          ssum[qt] += p[st][r];
        }
      // redistribute P to PV A-frag layout (verified r4 routing, kk = 0)
      union { bf16 h8[8]; int d[4]; } pk;
#pragma unroll
      for (int dd = 0; dd < 4; ++dd) {
        pk.h8[2 * dd]     = (bf16)p[dd >> 1][2 * (dd & 1)];
        pk.h8[2 * dd + 1] = (bf16)p[dd >> 1][2 * (dd & 1) + 1];
      }
      const int rA0 = __builtin_amdgcn_ds_bpermute(idxA, pk.d[0]);
      const int rA2 = __builtin_amdgcn_ds_bpermute(idxA, pk.d[2]);
      const int rA1 = __builtin_amdgcn_ds_bpermute(idxA, pk.d[1]);
      const int rA3 = __builtin_amdgcn_ds_bpermute(idxA, pk.d[3]);
      const int rB0 = __builtin_amdgcn_ds_bpermute(idxB, pk.d[0]);
      const int rB2 = __builtin_amdgcn_ds_bpermute(idxB, pk.d[2]);
      const int rB1 = __builtin_amdgcn_ds_bpermute(idxB, pk.d[1]);
      const int rB3 = __builtin_amdgcn_ds_bpermute(idxB, pk.d[3]);
      union { bf16x8 v; int d[4]; } pa;
      pa.d[0] = (g >= 2) ? rA2 : rA0;
      pa.d[1] = (g >= 2) ? rA3 : rA1;
      pa.d[2] = (g >= 2) ? rB2 : rB0;
      pa.d[3] = (g >= 2) ? rB3 : rB1;
#pragma unroll
      for (int dt = 0; dt < 4; ++dt)
        acco[qt][dt] = mfma16(pa.v, vb[dt], acco[qt][dt]);
    }
  }

  // ---- merge the 4 waves' partial states ----
#pragma unroll
  for (int qt = 0; qt < 4; ++qt) {
    ssum[qt] += __shfl_xor(ssum[qt], 16);
    ssum[qt] += __shfl_xor(ssum[qt], 32);
  }
  __syncthreads();                            // main loop done; Vl dead
  if (g == 0) {
#pragma unroll
    for (int qt = 0; qt < 4; ++qt) {
      sh.m.ml[w][0][qt * 16 + l15] = mx[qt];
      sh.m.ml[w][1][qt * 16 + l15] = ssum[qt];
    }
  }
  __syncthreads();
  // own rescale factor for q-rows this lane holds (q = qt*16 + g*4 + r)
  float fown[4][4];
#pragma unroll
  for (int qt = 0; qt < 4; ++qt)
#pragma unroll
    for (int r = 0; r < 4; ++r) {
      const int ql = qt * 16 + gq4 + r;
      const float m0 = sh.m.ml[0][0][ql], m1 = sh.m.ml[1][0][ql];
      const float m2 = sh.m.ml[2][0][ql], m3 = sh.m.ml[3][0][ql];
      const float mst = fmaxf(fmaxf(m0, m1), fmaxf(m2, m3));
      fown[qt][r] = fexp2(sh.m.ml[w][0][ql] - mst);
    }
  // serialized accumulation rounds (deterministic)
  for (int rd = 0; rd < 4; ++rd) {
    if (w == rd) {
#pragma unroll
      for (int qt = 0; qt < 4; ++qt)
#pragma unroll
        for (int dt = 0; dt < 4; ++dt)
#pragma unroll
          for (int r = 0; r < 4; ++r) {
            const int o = (qt * 16 + gq4 + r) * 68 + dt * 16 + l15;
            const float val = acco[qt][dt][r] * fown[qt][r];
            if (rd == 0) sh.m.o[o] = val;
            else         sh.m.o[o] += val;
          }
    }
    __syncthreads();
  }
  // normalize + write: wave w handles q-rows [16w, 16w+16)
  {
    const int ql = w * 16 + l15;
    float M[4], L[4];
#pragma unroll
    for (int j = 0; j < 4; ++j) {
      M[j] = sh.m.ml[j][0][ql];
      L[j] = sh.m.ml[j][1][ql];
    }
    const float mst = fmaxf(fmaxf(M[0], M[1]), fmaxf(M[2], M[3]));
    const float lst = L[0] * fexp2(M[0] - mst) + L[1] * fexp2(M[1] - mst) +
                      L[2] * fexp2(M[2] - mst) + L[3] * fexp2(M[3] - mst);
    const float inv = 1.0f / lst;
    const float* orow = &sh.m.o[ql * 68 + g * 16];
    const f32x4 o0 = *(const f32x4*)orow;
    const f32x4 o1 = *(const f32x4*)(orow + 4);
    const f32x4 o2 = *(const f32x4*)(orow + 8);
    const f32x4 o3 = *(const f32x4*)(orow + 12);
    bf16x8 w0, w1;
#pragma unroll
    for (int j = 0; j < 4; ++j) {
      w0[j]     = (bf16)(o0[j] * inv);
      w0[4 + j] = (bf16)(o1[j] * inv);
      w1[j]     = (bf16)(o2[j] * inv);
      w1[4 + j] = (bf16)(o3[j] * inv);
    }
    bf16* xp = Xw + (size_t)(b * SS + q0 + ql) * DD + h * 64 + g * 16;
    *(bf16x8*)xp = w0;
    *(bf16x8*)(xp + 8) = w1;
  }
}

// ---------------- launch ----------------
extern "C" void kernel_launch(void* const* d_in, const int* in_sizes, int n_in,
                              void* d_out, int out_size, void* d_ws, size_t ws_size,
                              hipStream_t stream) {
  const float* q32 = (const float*)d_in[0];
  const float* k32 = (const float*)d_in[1];
  const float* v32 = (const float*)d_in[2];
  const int* mask = (const int*)d_in[3];
  const float* Wq = (const float*)d_in[4];
  const float* Wk = (const float*)d_in[5];
  const float* Wv = (const float*)d_in[6];
  const float* Wo = (const float*)d_in[7];
  float* out = (float*)d_out;

  bf16* Qb = (bf16*)d_ws;
  bf16* Kb = Qb + (size_t)MM * DD;
  bf16* Vb = Kb + (size_t)MM * DD;
  bf16* Xb = Vb + (size_t)MM * DD;
  unsigned* mbits = (unsigned*)(Xb + (size_t)MM * DD);

  k_mask_bits<<<BB * SS, 256, 0, stream>>>(mask, mbits);
  k_gemm_qkv<<<dim3((MM / 128) * (DD / 128), 1, 3), 256, 0, stream>>>(
      q32, k32, v32, Wq, Wk, Wv, Qb, Kb, Vb);
  k_attn<<<BB * HH * (SS / 64), 256, 0, stream>>>(Qb, Kb, Vb, mbits, Xb);
  k_gemm_out<<<(MM / 128) * (DD / 128), 256, 0, stream>>>(Xb, Wo, out);
}

// Round 6
// 154.001 us; speedup vs baseline: 1.1859x; 1.1859x over previous
//
#include <hip/hip_runtime.h>

#define BB 4
#define SS 1024
#define DD 1024
#define HH 16
#define DKK 64
#define MM (BB*SS)   // 4096

typedef __bf16 bf16;
typedef __bf16 bf16x8 __attribute__((ext_vector_type(8)));
typedef float f32x4 __attribute__((ext_vector_type(4)));

__device__ __forceinline__ f32x4 mfma16(bf16x8 a, bf16x8 b, f32x4 c) {
  return __builtin_amdgcn_mfma_f32_16x16x32_bf16(a, b, c, 0, 0, 0);
}

__device__ __forceinline__ float fexp2(float x) {
  return __builtin_amdgcn_exp2f(x);
}

// async global->LDS, 16B per lane; LDS dest must be wave-uniform base.
__device__ __forceinline__ void gld_lds16(const bf16* g, bf16* l) {
  __builtin_amdgcn_global_load_lds(
      (const __attribute__((address_space(1))) void*)g,
      (__attribute__((address_space(3))) void*)l, 16, 0, 0);
}

// ---------------- fp32 -> bf16 convert (6 tensors) ----------------
__global__ __launch_bounds__(256)
void k_cvt6(const float* __restrict__ s0, const float* __restrict__ s1,
            const float* __restrict__ s2, const float* __restrict__ s3,
            const float* __restrict__ s4, const float* __restrict__ s5,
            bf16* __restrict__ d0, bf16* __restrict__ d1, bf16* __restrict__ d2,
            bf16* __restrict__ d3, bf16* __restrict__ d4, bf16* __restrict__ d5) {
  const int t = blockIdx.y;
  const float* s = (t == 0) ? s0 : (t == 1) ? s1 : (t == 2) ? s2
                 : (t == 3) ? s3 : (t == 4) ? s4 : s5;
  bf16* d = (t == 0) ? d0 : (t == 1) ? d1 : (t == 2) ? d2
          : (t == 3) ? d3 : (t == 4) ? d4 : d5;
  const int n = (t < 3) ? (MM * DD) : (DD * DD);
  const int i0 = (blockIdx.x * 256 + threadIdx.x) * 8;
  if (i0 >= n) return;
  const f32x4 a = *(const f32x4*)(s + i0);
  const f32x4 b = *(const f32x4*)(s + i0 + 4);
  bf16x8 o;
#pragma unroll
  for (int j = 0; j < 4; ++j) { o[j] = (bf16)a[j]; o[4 + j] = (bf16)b[j]; }
  *(bf16x8*)(d + i0) = o;
}

// ---------------- mask -> bitmask ----------------
__global__ __launch_bounds__(256) void k_mask_bits(const int* __restrict__ mask,
                                                   unsigned* __restrict__ bits) {
  const int row = blockIdx.x;
  const int tid = threadIdx.x;
  const int lane = tid & 63, wv = tid >> 6;
#pragma unroll
  for (int it = 0; it < 4; ++it) {
    const int base = it * 256 + wv * 64;
    const int col = base + lane;
    unsigned long long bal = __ballot(mask[(size_t)row * SS + col] != 0);
    if (lane == 0) {
      bits[(size_t)row * 32 + (base >> 5)] = (unsigned)bal;
      bits[(size_t)row * 32 + (base >> 5) + 1] = (unsigned)(bal >> 32);
    }
  }
}

// Q is pre-scaled by 1/sqrt(dk) * log2(e) so attention works in exp2 domain.
#define QSCALE 0.1803368801111204f

// ---------------- legacy GEMM  C = (A @ W^T) * oscale (fp32 W staging) -----
template<int AF32, int CF32>
__device__ __forceinline__ void gemm_body(const void* __restrict__ Ap,
                                          const float* __restrict__ Wp,
                                          void* __restrict__ Cp,
                                          int Mtot, int N, int K, int blk,
                                          float oscale) {
  __shared__ bf16 Al[128 * 40];
  __shared__ bf16 Bl[128 * 40];
  const int tid = threadIdx.x;
  const int lane = tid & 63;
  const int l15 = lane & 15, l4 = lane >> 4;
  const int wv = tid >> 6;
  const int nbm = Mtot >> 7;
  const int bm = blk % nbm, bn = blk / nbm;
  const size_t m0 = (size_t)bm << 7, n0 = (size_t)bn << 7;
  const int wr = (wv >> 1) << 6, wc = (wv & 1) << 6;
  const int srow = tid >> 2, scol = (tid & 3) << 3;

  f32x4 acc[4][4];
#pragma unroll
  for (int i = 0; i < 4; ++i)
#pragma unroll
    for (int j = 0; j < 4; ++j) acc[i][j] = f32x4{0.f, 0.f, 0.f, 0.f};

  for (int k0 = 0; k0 < K; k0 += 32) {
#pragma unroll
    for (int c = 0; c < 2; ++c) {
      const int row = (c << 6) + srow;
      bf16x8 av;
      if (AF32) {
        const float* s = (const float*)Ap + (m0 + row) * (size_t)K + k0 + scol;
        f32x4 v0 = *(const f32x4*)s;
        f32x4 v1 = *(const f32x4*)(s + 4);
#pragma unroll
        for (int j = 0; j < 4; ++j) { av[j] = (bf16)v0[j]; av[4 + j] = (bf16)v1[j]; }
      } else {
        av = *(const bf16x8*)((const bf16*)Ap + (m0 + row) * (size_t)K + k0 + scol);
      }
      *(bf16x8*)&Al[row * 40 + scol] = av;

      const float* ws_ = Wp + (n0 + row) * (size_t)K + k0 + scol;
      f32x4 w0 = *(const f32x4*)ws_;
      f32x4 w1 = *(const f32x4*)(ws_ + 4);
      bf16x8 wv8;
#pragma unroll
      for (int j = 0; j < 4; ++j) { wv8[j] = (bf16)w0[j]; wv8[4 + j] = (bf16)w1[j]; }
      *(bf16x8*)&Bl[row * 40 + scol] = wv8;
    }
    __syncthreads();

    bf16x8 af[4], bfv[4];
#pragma unroll
    for (int t = 0; t < 4; ++t) {
      af[t]  = *(const bf16x8*)&Al[(wr + t * 16 + l15) * 40 + l4 * 8];
      bfv[t] = *(const bf16x8*)&Bl[(wc + t * 16 + l15) * 40 + l4 * 8];
    }
    __builtin_amdgcn_s_setprio(1);
#pragma unroll
    for (int mt = 0; mt < 4; ++mt)
#pragma unroll
      for (int nt = 0; nt < 4; ++nt)
        acc[mt][nt] = mfma16(af[mt], bfv[nt], acc[mt][nt]);
    __builtin_amdgcn_s_setprio(0);
    __syncthreads();
  }

#pragma unroll
  for (int mt = 0; mt < 4; ++mt)
#pragma unroll
    for (int nt = 0; nt < 4; ++nt)
#pragma unroll
      for (int r = 0; r < 4; ++r) {
        const size_t row = m0 + wr + mt * 16 + l4 * 4 + r;
        const size_t col = n0 + wc + nt * 16 + l15;
        if (CF32) ((float*)Cp)[row * N + col] = acc[mt][nt][r];
        else      ((bf16*)Cp)[row * N + col] = (bf16)(acc[mt][nt][r] * oscale);
      }
}

__global__ __launch_bounds__(256)
void k_gemm_qkv(const float* __restrict__ A0, const float* __restrict__ A1,
                const float* __restrict__ A2, const float* __restrict__ W0,
                const float* __restrict__ W1, const float* __restrict__ W2,
                bf16* __restrict__ C0, bf16* __restrict__ C1, bf16* __restrict__ C2) {
  const int z = blockIdx.z;
  const float* A = (z == 0) ? A0 : (z == 1) ? A1 : A2;
  const float* W = (z == 0) ? W0 : (z == 1) ? W1 : W2;
  bf16* C = (z == 0) ? C0 : (z == 1) ? C1 : C2;
  const float sc = (z == 0) ? QSCALE : 1.0f;
  gemm_body<1, 0>(A, W, C, MM, DD, DD, blockIdx.x, sc);
}

__global__ __launch_bounds__(256)
void k_gemm_out(const bf16* __restrict__ A, const float* __restrict__ W,
                float* __restrict__ C) {
  gemm_body<0, 1>(A, W, C, MM, DD, DD, blockIdx.x, 1.0f);
}

// ---------------- bf16 GEMM with global_load_lds (m97 structure) ----------
// A [4096,1024] bf16, W [1024,1024] bf16 (torch layout, C = A@W^T), C bf16.
// 128x128 tile, BK=32, 4 waves 2x2, LDS linear [128][32].
__global__ __launch_bounds__(256)
void k_gemm_qkv_b16(const bf16* __restrict__ A0, const bf16* __restrict__ A1,
                    const bf16* __restrict__ A2, const bf16* __restrict__ W0,
                    const bf16* __restrict__ W1, const bf16* __restrict__ W2,
                    bf16* __restrict__ C0, bf16* __restrict__ C1,
                    bf16* __restrict__ C2) {
  __shared__ bf16 Al[128 * 32];
  __shared__ bf16 Bl[128 * 32];
  const int z = blockIdx.z;
  const bf16* A = (z == 0) ? A0 : (z == 1) ? A1 : A2;
  const bf16* W = (z == 0) ? W0 : (z == 1) ? W1 : W2;
  bf16* C = (z == 0) ? C0 : (z == 1) ? C1 : C2;
  const float oscale = (z == 0) ? QSCALE : 1.0f;

  const int tid = threadIdx.x, lane = tid & 63, w = tid >> 6;
  const int l15 = lane & 15, l4 = lane >> 4;
  const int bm = blockIdx.x & 31, bn = blockIdx.x >> 5;
  const size_t m0 = (size_t)bm << 7, n0 = (size_t)bn << 7;
  const int wr = (w >> 1) << 6, wc = (w & 1) << 6;
  const int srow = w * 32 + (lane >> 2);   // staging row this lane covers
  const int scol = (lane & 3) << 3;

  f32x4 acc[4][4];
#pragma unroll
  for (int i = 0; i < 4; ++i)
#pragma unroll
    for (int j = 0; j < 4; ++j) acc[i][j] = f32x4{0.f, 0.f, 0.f, 0.f};

  for (int k0 = 0; k0 < DD; k0 += 32) {
    const bf16* ga = A + (m0 + srow) * (size_t)DD + k0 + scol;
    const bf16* gb = W + (n0 + srow) * (size_t)DD + k0 + scol;
    gld_lds16(ga,            &Al[(w * 32) * 32]);
    gld_lds16(ga + 16 * DD,  &Al[(w * 32 + 16) * 32]);
    gld_lds16(gb,            &Bl[(w * 32) * 32]);
    gld_lds16(gb + 16 * DD,  &Bl[(w * 32 + 16) * 32]);
    __syncthreads();

    bf16x8 af[4], bfv[4];
#pragma unroll
    for (int t = 0; t < 4; ++t) {
      af[t]  = *(const bf16x8*)&Al[(wr + t * 16 + l15) * 32 + l4 * 8];
      bfv[t] = *(const bf16x8*)&Bl[(wc + t * 16 + l15) * 32 + l4 * 8];
    }
#pragma unroll
    for (int mt = 0; mt < 4; ++mt)
#pragma unroll
      for (int nt = 0; nt < 4; ++nt)
        acc[mt][nt] = mfma16(af[mt], bfv[nt], acc[mt][nt]);
    __syncthreads();
  }

#pragma unroll
  for (int mt = 0; mt < 4; ++mt)
#pragma unroll
    for (int nt = 0; nt < 4; ++nt)
#pragma unroll
      for (int r = 0; r < 4; ++r) {
        const size_t row = m0 + wr + mt * 16 + l4 * 4 + r;
        const size_t col = n0 + wc + nt * 16 + l15;
        C[row * DD + col] = (bf16)(acc[mt][nt][r] * oscale);
      }
}

// ---------------- flash attention, split-kv across waves ----------------
#define VKS 34
__global__ __launch_bounds__(256)
void k_attn(const bf16* __restrict__ Qw, const bf16* __restrict__ Kw,
            const bf16* __restrict__ Vw, const unsigned* __restrict__ mb,
            bf16* __restrict__ Xw) {
  __shared__ union {
    bf16 v[4][64 * VKS];
    struct { float o[64 * 68]; float ml[4][2][64]; } m;
  } sh;
  const int tid = threadIdx.x, lane = tid & 63, w = tid >> 6;
  const int l15 = lane & 15, g = lane >> 4, gq4 = g << 2;
  const unsigned bid = blockIdx.x;
  const int bh = ((bid & 7) << 3) + (bid >> 7);
  const int qt_blk = (bid >> 3) & 15;
  const int h = bh & 15, b = bh >> 4;
  const int q0 = qt_blk * 64;

  bf16x8 qf[4][2];
  {
    const bf16* Qb = Qw + (size_t)(b * SS + q0 + l15) * DD + h * 64 + g * 8;
#pragma unroll
    for (int qt = 0; qt < 4; ++qt) {
      qf[qt][0] = *(const bf16x8*)(Qb + (size_t)qt * 16 * DD);
      qf[qt][1] = *(const bf16x8*)(Qb + (size_t)qt * 16 * DD + 32);
    }
  }
  const bf16* Kb = Kw + (size_t)(b * SS) * DD + h * 64 + g * 8;
  const bf16* Vbp = Vw + (size_t)(b * SS) * DD + h * 64 + l15 * 4;
  const unsigned* mbase = mb + (size_t)(b * SS + q0 + l15) * 32;

  f32x4 acco[4][4];
#pragma unroll
  for (int qt = 0; qt < 4; ++qt)
#pragma unroll
    for (int dt = 0; dt < 4; ++dt) acco[qt][dt] = f32x4{0.f, 0.f, 0.f, 0.f};
  float mx[4], ssum[4];
#pragma unroll
  for (int qt = 0; qt < 4; ++qt) { mx[qt] = -3e38f; ssum[qt] = 0.f; }

  bf16* Vl = sh.v[w];
  const int idxA = (l15 + ((g & 1) << 5)) << 2;
  const int idxB = idxA + 64;
  const int kvw = w << 8;

  for (int it = 0; it < 8; ++it) {
    const int kv0 = kvw + it * 32;
    union { uint2 u; bf16 h4[4]; } vld[8];
#pragma unroll
    for (int i = 0; i < 8; ++i)
      vld[i].u = *(const uint2*)(Vbp + (size_t)(kv0 + i * 4 + g) * DD);
    bf16x8 kf[2][2];
#pragma unroll
    for (int st = 0; st < 2; ++st) {
      const bf16* kp = Kb + (size_t)(kv0 + st * 16 + l15) * DD;
      kf[st][0] = *(const bf16x8*)kp;
      kf[st][1] = *(const bf16x8*)(kp + 32);
    }
    unsigned mwd[4];
#pragma unroll
    for (int qt = 0; qt < 4; ++qt)
      mwd[qt] = mbase[(size_t)(qt * 16) * 32 + (kv0 >> 5)];
#pragma unroll
    for (int i = 0; i < 8; ++i)
#pragma unroll
      for (int j = 0; j < 4; ++j)
        Vl[(l15 * 4 + j) * VKS + i * 4 + g] = vld[i].h4[j];
    bf16x8 vb[4];
#pragma unroll
    for (int dt = 0; dt < 4; ++dt)
      vb[dt] = *(const bf16x8*)&Vl[(dt * 16 + l15) * VKS + g * 8];

#pragma unroll
    for (int qt = 0; qt < 4; ++qt) {
      f32x4 s0 = f32x4{0.f, 0.f, 0.f, 0.f}, s1 = f32x4{0.f, 0.f, 0.f, 0.f};
      s0 = mfma16(kf[0][0], qf[qt][0], s0);
      s0 = mfma16(kf[0][1], qf[qt][1], s0);
      s1 = mfma16(kf[1][0], qf[qt][0], s1);
      s1 = mfma16(kf[1][1], qf[qt][1], s1);
      float p[2][4];
#pragma unroll
      for (int r = 0; r < 4; ++r) {
        p[0][r] = ((mwd[qt] >> (gq4 + r)) & 1) ? s0[r] : -1e9f;
        p[1][r] = ((mwd[qt] >> (16 + gq4 + r)) & 1) ? s1[r] : -1e9f;
      }
      float rm = fmaxf(fmaxf(fmaxf(p[0][0], p[0][1]), fmaxf(p[0][2], p[0][3])),
                       fmaxf(fmaxf(p[1][0], p[1][1]), fmaxf(p[1][2], p[1][3])));
      rm = fmaxf(rm, __shfl_xor(rm, 16));
      rm = fmaxf(rm, __shfl_xor(rm, 32));
      if (!__all(rm <= mx[qt] + 8.0f)) {
        const float mn = fmaxf(mx[qt], rm);
        const float scal = fexp2(mx[qt] - mn);
        mx[qt] = mn;
        ssum[qt] *= scal;
        const float s0f = __shfl(scal, gq4);
        const float s1f = __shfl(scal, gq4 + 1);
        const float s2f = __shfl(scal, gq4 + 2);
        const float s3f = __shfl(scal, gq4 + 3);
#pragma unroll
        for (int dt = 0; dt < 4; ++dt) {
          acco[qt][dt][0] *= s0f; acco[qt][dt][1] *= s1f;
          acco[qt][dt][2] *= s2f; acco[qt][dt][3] *= s3f;
        }
      }
#pragma unroll
      for (int st = 0; st < 2; ++st)
#pragma unroll
        for (int r = 0; r < 4; ++r) {
          p[st][r] = fexp2(p[st][r] - mx[qt]);
          ssum[qt] += p[st][r];
        }
      union { bf16 h8[8]; int d[4]; } pk;
#pragma unroll
      for (int dd = 0; dd < 4; ++dd) {
        pk.h8[2 * dd]     = (bf16)p[dd >> 1][2 * (dd & 1)];
        pk.h8[2 * dd + 1] = (bf16)p[dd >> 1][2 * (dd & 1) + 1];
      }
      const int rA0 = __builtin_amdgcn_ds_bpermute(idxA, pk.d[0]);
      const int rA2 = __builtin_amdgcn_ds_bpermute(idxA, pk.d[2]);
      const int rA1 = __builtin_amdgcn_ds_bpermute(idxA, pk.d[1]);
      const int rA3 = __builtin_amdgcn_ds_bpermute(idxA, pk.d[3]);
      const int rB0 = __builtin_amdgcn_ds_bpermute(idxB, pk.d[0]);
      const int rB2 = __builtin_amdgcn_ds_bpermute(idxB, pk.d[2]);
      const int rB1 = __builtin_amdgcn_ds_bpermute(idxB, pk.d[1]);
      const int rB3 = __builtin_amdgcn_ds_bpermute(idxB, pk.d[3]);
      union { bf16x8 v; int d[4]; } pa;
      pa.d[0] = (g >= 2) ? rA2 : rA0;
      pa.d[1] = (g >= 2) ? rA3 : rA1;
      pa.d[2] = (g >= 2) ? rB2 : rB0;
      pa.d[3] = (g >= 2) ? rB3 : rB1;
#pragma unroll
      for (int dt = 0; dt < 4; ++dt)
        acco[qt][dt] = mfma16(pa.v, vb[dt], acco[qt][dt]);
    }
  }

#pragma unroll
  for (int qt = 0; qt < 4; ++qt) {
    ssum[qt] += __shfl_xor(ssum[qt], 16);
    ssum[qt] += __shfl_xor(ssum[qt], 32);
  }
  __syncthreads();
  if (g == 0) {
#pragma unroll
    for (int qt = 0; qt < 4; ++qt) {
      sh.m.ml[w][0][qt * 16 + l15] = mx[qt];
      sh.m.ml[w][1][qt * 16 + l15] = ssum[qt];
    }
  }
  __syncthreads();
  float fown[4][4];
#pragma unroll
  for (int qt = 0; qt < 4; ++qt)
#pragma unroll
    for (int r = 0; r < 4; ++r) {
      const int ql = qt * 16 + gq4 + r;
      const float m0 = sh.m.ml[0][0][ql], m1 = sh.m.ml[1][0][ql];
      const float m2 = sh.m.ml[2][0][ql], m3 = sh.m.ml[3][0][ql];
      const float mst = fmaxf(fmaxf(m0, m1), fmaxf(m2, m3));
      fown[qt][r] = fexp2(sh.m.ml[w][0][ql] - mst);
    }
  for (int rd = 0; rd < 4; ++rd) {
    if (w == rd) {
#pragma unroll
      for (int qt = 0; qt < 4; ++qt)
#pragma unroll
        for (int dt = 0; dt < 4; ++dt)
#pragma unroll
          for (int r = 0; r < 4; ++r) {
            const int o = (qt * 16 + gq4 + r) * 68 + dt * 16 + l15;
            const float val = acco[qt][dt][r] * fown[qt][r];
            if (rd == 0) sh.m.o[o] = val;
            else         sh.m.o[o] += val;
          }
    }
    __syncthreads();
  }
  {
    const int ql = w * 16 + l15;
    float M[4], L[4];
#pragma unroll
    for (int j = 0; j < 4; ++j) {
      M[j] = sh.m.ml[j][0][ql];
      L[j] = sh.m.ml[j][1][ql];
    }
    const float mst = fmaxf(fmaxf(M[0], M[1]), fmaxf(M[2], M[3]));
    const float lst = L[0] * fexp2(M[0] - mst) + L[1] * fexp2(M[1] - mst) +
                      L[2] * fexp2(M[2] - mst) + L[3] * fexp2(M[3] - mst);
    const float inv = 1.0f / lst;
    const float* orow = &sh.m.o[ql * 68 + g * 16];
    const f32x4 o0 = *(const f32x4*)orow;
    const f32x4 o1 = *(const f32x4*)(orow + 4);
    const f32x4 o2 = *(const f32x4*)(orow + 8);
    const f32x4 o3 = *(const f32x4*)(orow + 12);
    bf16x8 w0, w1;
#pragma unroll
    for (int j = 0; j < 4; ++j) {
      w0[j]     = (bf16)(o0[j] * inv);
      w0[4 + j] = (bf16)(o1[j] * inv);
      w1[j]     = (bf16)(o2[j] * inv);
      w1[4 + j] = (bf16)(o3[j] * inv);
    }
    bf16* xp = Xw + (size_t)(b * SS + q0 + ql) * DD + h * 64 + g * 16;
    *(bf16x8*)xp = w0;
    *(bf16x8*)(xp + 8) = w1;
  }
}

// ---------------- launch ----------------
extern "C" void kernel_launch(void* const* d_in, const int* in_sizes, int n_in,
                              void* d_out, int out_size, void* d_ws, size_t ws_size,
                              hipStream_t stream) {
  const float* q32 = (const float*)d_in[0];
  const float* k32 = (const float*)d_in[1];
  const float* v32 = (const float*)d_in[2];
  const int* mask = (const int*)d_in[3];
  const float* Wq = (const float*)d_in[4];
  const float* Wk = (const float*)d_in[5];
  const float* Wv = (const float*)d_in[6];
  const float* Wo = (const float*)d_in[7];
  float* out = (float*)d_out;

  const size_t eAct = (size_t)MM * DD;   // bf16 elems per activation
  const size_t eW = (size_t)DD * DD;

  bf16* Qb = (bf16*)d_ws;
  bf16* Kb = Qb + eAct;
  bf16* Vb = Kb + eAct;
  bf16* Xb = Vb + eAct;
  unsigned* mbits = (unsigned*)(Xb + eAct);
  bf16* cvtBase = (bf16*)(mbits + (size_t)MM * 32);
  bf16* Aq = cvtBase;
  bf16* Ak = Aq + eAct;
  bf16* Av = Ak + eAct;
  bf16* Wqb = Av + eAct;
  bf16* Wkb = Wqb + eW;
  bf16* Wvb = Wkb + eW;
  const size_t need = (size_t)((bf16*)(Wvb + eW) - (bf16*)d_ws) * sizeof(bf16);

  k_mask_bits<<<BB * SS, 256, 0, stream>>>(mask, mbits);
  if (ws_size >= need) {
    k_cvt6<<<dim3(2048, 6), 256, 0, stream>>>(q32, k32, v32, Wq, Wk, Wv,
                                              Aq, Ak, Av, Wqb, Wkb, Wvb);
    k_gemm_qkv_b16<<<dim3(256, 1, 3), 256, 0, stream>>>(
        Aq, Ak, Av, Wqb, Wkb, Wvb, Qb, Kb, Vb);
  } else {
    k_gemm_qkv<<<dim3((MM / 128) * (DD / 128), 1, 3), 256, 0, stream>>>(
        q32, k32, v32, Wq, Wk, Wv, Qb, Kb, Vb);
  }
  k_attn<<<BB * HH * (SS / 64), 256, 0, stream>>>(Qb, Kb, Vb, mbits, Xb);
  k_gemm_out<<<(MM / 128) * (DD / 128), 256, 0, stream>>>(Xb, Wo, out);
}

// Round 7
// 148.182 us; speedup vs baseline: 1.2325x; 1.0393x over previous
//
#include <hip/hip_runtime.h>

#define BB 4
#define SS 1024
#define DD 1024
#define HH 16
#define DKK 64
#define MM (BB*SS)   // 4096

typedef __bf16 bf16;
typedef __bf16 bf16x8 __attribute__((ext_vector_type(8)));
typedef float f32x4 __attribute__((ext_vector_type(4)));
typedef float f32x16 __attribute__((ext_vector_type(16)));

__device__ __forceinline__ f32x4 mfma16(bf16x8 a, bf16x8 b, f32x4 c) {
  return __builtin_amdgcn_mfma_f32_16x16x32_bf16(a, b, c, 0, 0, 0);
}
__device__ __forceinline__ f32x16 mfma32(bf16x8 a, bf16x8 b, f32x16 c) {
  return __builtin_amdgcn_mfma_f32_32x32x16_bf16(a, b, c, 0, 0, 0);
}
__device__ __forceinline__ float fexp2(float x) {
  return __builtin_amdgcn_exp2f(x);
}
__device__ __forceinline__ void gld_lds16(const bf16* g, bf16* l) {
  __builtin_amdgcn_global_load_lds(
      (const __attribute__((address_space(1))) void*)g,
      (__attribute__((address_space(3))) void*)l, 16, 0, 0);
}

// ---------------- fp32 -> bf16 convert (7 tensors) ----------------
__global__ __launch_bounds__(256)
void k_cvt7(const float* __restrict__ s0, const float* __restrict__ s1,
            const float* __restrict__ s2, const float* __restrict__ s3,
            const float* __restrict__ s4, const float* __restrict__ s5,
            const float* __restrict__ s6,
            bf16* __restrict__ d0, bf16* __restrict__ d1, bf16* __restrict__ d2,
            bf16* __restrict__ d3, bf16* __restrict__ d4, bf16* __restrict__ d5,
            bf16* __restrict__ d6) {
  const int t = blockIdx.y;
  const float* s = (t == 0) ? s0 : (t == 1) ? s1 : (t == 2) ? s2
                 : (t == 3) ? s3 : (t == 4) ? s4 : (t == 5) ? s5 : s6;
  bf16* d = (t == 0) ? d0 : (t == 1) ? d1 : (t == 2) ? d2
          : (t == 3) ? d3 : (t == 4) ? d4 : (t == 5) ? d5 : d6;
  const int n = (t < 3) ? (MM * DD) : (DD * DD);
  const int i0 = (blockIdx.x * 256 + threadIdx.x) * 8;
  if (i0 >= n) return;
  const f32x4 a = *(const f32x4*)(s + i0);
  const f32x4 b = *(const f32x4*)(s + i0 + 4);
  bf16x8 o;
#pragma unroll
  for (int j = 0; j < 4; ++j) { o[j] = (bf16)a[j]; o[4 + j] = (bf16)b[j]; }
  *(bf16x8*)(d + i0) = o;
}

// ---------------- mask -> bitmask ----------------
__global__ __launch_bounds__(256) void k_mask_bits(const int* __restrict__ mask,
                                                   unsigned* __restrict__ bits) {
  const int row = blockIdx.x;
  const int tid = threadIdx.x;
  const int lane = tid & 63, wv = tid >> 6;
#pragma unroll
  for (int it = 0; it < 4; ++it) {
    const int base = it * 256 + wv * 64;
    const int col = base + lane;
    unsigned long long bal = __ballot(mask[(size_t)row * SS + col] != 0);
    if (lane == 0) {
      bits[(size_t)row * 32 + (base >> 5)] = (unsigned)bal;
      bits[(size_t)row * 32 + (base >> 5) + 1] = (unsigned)(bal >> 32);
    }
  }
}

// Q pre-scaled by 1/sqrt(dk) * log2(e): attention runs in exp2 domain.
#define QSCALE 0.1803368801111204f

// ---------------- legacy GEMM (fallback when ws too small) ----------------
template<int AF32, int CF32>
__device__ __forceinline__ void gemm_body(const void* __restrict__ Ap,
                                          const float* __restrict__ Wp,
                                          void* __restrict__ Cp,
                                          int Mtot, int N, int K, int blk,
                                          float oscale) {
  __shared__ bf16 Al[128 * 40];
  __shared__ bf16 Bl[128 * 40];
  const int tid = threadIdx.x;
  const int lane = tid & 63;
  const int l15 = lane & 15, l4 = lane >> 4;
  const int wv = tid >> 6;
  const int nbm = Mtot >> 7;
  const int bm = blk % nbm, bn = blk / nbm;
  const size_t m0 = (size_t)bm << 7, n0 = (size_t)bn << 7;
  const int wr = (wv >> 1) << 6, wc = (wv & 1) << 6;
  const int srow = tid >> 2, scol = (tid & 3) << 3;

  f32x4 acc[4][4];
#pragma unroll
  for (int i = 0; i < 4; ++i)
#pragma unroll
    for (int j = 0; j < 4; ++j) acc[i][j] = f32x4{0.f, 0.f, 0.f, 0.f};

  for (int k0 = 0; k0 < K; k0 += 32) {
#pragma unroll
    for (int c = 0; c < 2; ++c) {
      const int row = (c << 6) + srow;
      bf16x8 av;
      if (AF32) {
        const float* s = (const float*)Ap + (m0 + row) * (size_t)K + k0 + scol;
        f32x4 v0 = *(const f32x4*)s;
        f32x4 v1 = *(const f32x4*)(s + 4);
#pragma unroll
        for (int j = 0; j < 4; ++j) { av[j] = (bf16)v0[j]; av[4 + j] = (bf16)v1[j]; }
      } else {
        av = *(const bf16x8*)((const bf16*)Ap + (m0 + row) * (size_t)K + k0 + scol);
      }
      *(bf16x8*)&Al[row * 40 + scol] = av;

      const float* ws_ = Wp + (n0 + row) * (size_t)K + k0 + scol;
      f32x4 w0 = *(const f32x4*)ws_;
      f32x4 w1 = *(const f32x4*)(ws_ + 4);
      bf16x8 wv8;
#pragma unroll
      for (int j = 0; j < 4; ++j) { wv8[j] = (bf16)w0[j]; wv8[4 + j] = (bf16)w1[j]; }
      *(bf16x8*)&Bl[row * 40 + scol] = wv8;
    }
    __syncthreads();

    bf16x8 af[4], bfv[4];
#pragma unroll
    for (int t = 0; t < 4; ++t) {
      af[t]  = *(const bf16x8*)&Al[(wr + t * 16 + l15) * 40 + l4 * 8];
      bfv[t] = *(const bf16x8*)&Bl[(wc + t * 16 + l15) * 40 + l4 * 8];
    }
    __builtin_amdgcn_s_setprio(1);
#pragma unroll
    for (int mt = 0; mt < 4; ++mt)
#pragma unroll
      for (int nt = 0; nt < 4; ++nt)
        acc[mt][nt] = mfma16(af[mt], bfv[nt], acc[mt][nt]);
    __builtin_amdgcn_s_setprio(0);
    __syncthreads();
  }

#pragma unroll
  for (int mt = 0; mt < 4; ++mt)
#pragma unroll
    for (int nt = 0; nt < 4; ++nt)
#pragma unroll
      for (int r = 0; r < 4; ++r) {
        const size_t row = m0 + wr + mt * 16 + l4 * 4 + r;
        const size_t col = n0 + wc + nt * 16 + l15;
        if (CF32) ((float*)Cp)[row * N + col] = acc[mt][nt][r];
        else      ((bf16*)Cp)[row * N + col] = (bf16)(acc[mt][nt][r] * oscale);
      }
}

__global__ __launch_bounds__(256)
void k_gemm_qkv(const float* __restrict__ A0, const float* __restrict__ A1,
                const float* __restrict__ A2, const float* __restrict__ W0,
                const float* __restrict__ W1, const float* __restrict__ W2,
                bf16* __restrict__ C0, bf16* __restrict__ C1, bf16* __restrict__ C2) {
  const int z = blockIdx.z;
  const float* A = (z == 0) ? A0 : (z == 1) ? A1 : A2;
  const float* W = (z == 0) ? W0 : (z == 1) ? W1 : W2;
  bf16* C = (z == 0) ? C0 : (z == 1) ? C1 : C2;
  const float sc = (z == 0) ? QSCALE : 1.0f;
  gemm_body<1, 0>(A, W, C, MM, DD, DD, blockIdx.x, sc);
}

__global__ __launch_bounds__(256)
void k_gemm_out(const bf16* __restrict__ A, const float* __restrict__ W,
                float* __restrict__ C) {
  gemm_body<0, 1>(A, W, C, MM, DD, DD, blockIdx.x, 1.0f);
}

// ---------------- bf16 GEMM with global_load_lds (m97 structure) ----------
__global__ __launch_bounds__(256)
void k_gemm_qkv_b16(const bf16* __restrict__ A0, const bf16* __restrict__ A1,
                    const bf16* __restrict__ A2, const bf16* __restrict__ W0,
                    const bf16* __restrict__ W1, const bf16* __restrict__ W2,
                    bf16* __restrict__ C0, bf16* __restrict__ C1,
                    bf16* __restrict__ C2) {
  __shared__ bf16 Al[128 * 32];
  __shared__ bf16 Bl[128 * 32];
  const int z = blockIdx.z;
  const bf16* A = (z == 0) ? A0 : (z == 1) ? A1 : A2;
  const bf16* W = (z == 0) ? W0 : (z == 1) ? W1 : W2;
  bf16* C = (z == 0) ? C0 : (z == 1) ? C1 : C2;
  const float oscale = (z == 0) ? QSCALE : 1.0f;

  const int tid = threadIdx.x, lane = tid & 63, w = tid >> 6;
  const int l15 = lane & 15, l4 = lane >> 4;
  const int bm = blockIdx.x & 31, bn = blockIdx.x >> 5;
  const size_t m0 = (size_t)bm << 7, n0 = (size_t)bn << 7;
  const int wr = (w >> 1) << 6, wc = (w & 1) << 6;
  const int srow = w * 32 + (lane >> 2);
  const int scol = (lane & 3) << 3;

  f32x4 acc[4][4];
#pragma unroll
  for (int i = 0; i < 4; ++i)
#pragma unroll
    for (int j = 0; j < 4; ++j) acc[i][j] = f32x4{0.f, 0.f, 0.f, 0.f};

  for (int k0 = 0; k0 < DD; k0 += 32) {
    const bf16* ga = A + (m0 + srow) * (size_t)DD + k0 + scol;
    const bf16* gb = W + (n0 + srow) * (size_t)DD + k0 + scol;
    gld_lds16(ga,            &Al[(w * 32) * 32]);
    gld_lds16(ga + 16 * DD,  &Al[(w * 32 + 16) * 32]);
    gld_lds16(gb,            &Bl[(w * 32) * 32]);
    gld_lds16(gb + 16 * DD,  &Bl[(w * 32 + 16) * 32]);
    __syncthreads();

    bf16x8 af[4], bfv[4];
#pragma unroll
    for (int t = 0; t < 4; ++t) {
      af[t]  = *(const bf16x8*)&Al[(wr + t * 16 + l15) * 32 + l4 * 8];
      bfv[t] = *(const bf16x8*)&Bl[(wc + t * 16 + l15) * 32 + l4 * 8];
    }
#pragma unroll
    for (int mt = 0; mt < 4; ++mt)
#pragma unroll
      for (int nt = 0; nt < 4; ++nt)
        acc[mt][nt] = mfma16(af[mt], bfv[nt], acc[mt][nt]);
    __syncthreads();
  }

#pragma unroll
  for (int mt = 0; mt < 4; ++mt)
#pragma unroll
    for (int nt = 0; nt < 4; ++nt)
#pragma unroll
      for (int r = 0; r < 4; ++r) {
        const size_t row = m0 + wr + mt * 16 + l4 * 4 + r;
        const size_t col = n0 + wc + nt * 16 + l15;
        C[row * DD + col] = (bf16)(acc[mt][nt][r] * oscale);
      }
}

__global__ __launch_bounds__(256)
void k_gemm_out_b16(const bf16* __restrict__ A, const bf16* __restrict__ W,
                    float* __restrict__ C) {
  __shared__ bf16 Al[128 * 32];
  __shared__ bf16 Bl[128 * 32];
  const int tid = threadIdx.x, lane = tid & 63, w = tid >> 6;
  const int l15 = lane & 15, l4 = lane >> 4;
  const int bm = blockIdx.x & 31, bn = blockIdx.x >> 5;
  const size_t m0 = (size_t)bm << 7, n0 = (size_t)bn << 7;
  const int wr = (w >> 1) << 6, wc = (w & 1) << 6;
  const int srow = w * 32 + (lane >> 2);
  const int scol = (lane & 3) << 3;

  f32x4 acc[4][4];
#pragma unroll
  for (int i = 0; i < 4; ++i)
#pragma unroll
    for (int j = 0; j < 4; ++j) acc[i][j] = f32x4{0.f, 0.f, 0.f, 0.f};

  for (int k0 = 0; k0 < DD; k0 += 32) {
    const bf16* ga = A + (m0 + srow) * (size_t)DD + k0 + scol;
    const bf16* gb = W + (n0 + srow) * (size_t)DD + k0 + scol;
    gld_lds16(ga,            &Al[(w * 32) * 32]);
    gld_lds16(ga + 16 * DD,  &Al[(w * 32 + 16) * 32]);
    gld_lds16(gb,            &Bl[(w * 32) * 32]);
    gld_lds16(gb + 16 * DD,  &Bl[(w * 32 + 16) * 32]);
    __syncthreads();

    bf16x8 af[4], bfv[4];
#pragma unroll
    for (int t = 0; t < 4; ++t) {
      af[t]  = *(const bf16x8*)&Al[(wr + t * 16 + l15) * 32 + l4 * 8];
      bfv[t] = *(const bf16x8*)&Bl[(wc + t * 16 + l15) * 32 + l4 * 8];
    }
#pragma unroll
    for (int mt = 0; mt < 4; ++mt)
#pragma unroll
      for (int nt = 0; nt < 4; ++nt)
        acc[mt][nt] = mfma16(af[mt], bfv[nt], acc[mt][nt]);
    __syncthreads();
  }

#pragma unroll
  for (int mt = 0; mt < 4; ++mt)
#pragma unroll
    for (int nt = 0; nt < 4; ++nt)
#pragma unroll
      for (int r = 0; r < 4; ++r) {
        const size_t row = m0 + wr + mt * 16 + l4 * 4 + r;
        const size_t col = n0 + wc + nt * 16 + l15;
        C[row * DD + col] = acc[mt][nt][r];
      }
}

// ------- flash attention: 32x32 MFMA, split-kv, XOR-32 P-routing ----------
// Block = 32 q rows, 4 waves each own a 256-kv quarter, KVBLK=32/iter.
// Swapped QK^T (mfma32(K,Q)): lane holds S[kv=(r&3)+8*(r>>2)+4*hi][q=lane&31].
// One softmax state per lane. P->A-frag needs only an XOR-32 lane exchange.
#define VKS 34
__global__ __launch_bounds__(256)
void k_attn(const bf16* __restrict__ Qw, const bf16* __restrict__ Kw,
            const bf16* __restrict__ Vw, const unsigned* __restrict__ mb,
            bf16* __restrict__ Xw) {
  __shared__ union {
    bf16 v[4][64 * VKS];                                  // 17408 B
    struct { float o[32 * 66]; float ml[4][2][32];
             float inv[32]; float mst[32]; } m;           // 9728 B
  } sh;
  const int tid = threadIdx.x, lane = tid & 63, w = tid >> 6;
  const int l31 = lane & 31, hi = lane >> 5;
  const int l15 = lane & 15, g = lane >> 4;
  const unsigned bid = blockIdx.x;
  const unsigned wg = (bid & 7) * 256 + (bid >> 3);  // XCD chunk swizzle (2048%8==0)
  const int bh = wg >> 5, qt = wg & 31;
  const int h = bh & 15, b = bh >> 4;
  const int q0 = qt * 32;

  bf16x8 qf[4];
  {
    const bf16* Qb = Qw + (size_t)(b * SS + q0 + l31) * DD + h * 64 + hi * 8;
#pragma unroll
    for (int kt = 0; kt < 4; ++kt) qf[kt] = *(const bf16x8*)(Qb + kt * 16);
  }
  const bf16* Kb = Kw + (size_t)(b * SS) * DD + h * 64 + hi * 8;
  const bf16* Vbp = Vw + (size_t)(b * SS) * DD + h * 64 + l15 * 4;
  const unsigned* mrow = mb + (size_t)(b * SS + q0 + l31) * 32 + w * 8;

  f32x16 acco[2];
#pragma unroll
  for (int dt = 0; dt < 2; ++dt)
#pragma unroll
    for (int r = 0; r < 16; ++r) acco[dt][r] = 0.f;
  float mx = -3e38f, ssum = 0.f;

  bf16* Vl = sh.v[w];
  const int kvw = w << 8;

  for (int it = 0; it < 8; ++it) {
    const int kv0 = kvw + it * 32;
    // V loads (coalesced along d), K A-frags, mask word
    union { uint2 u; bf16 h4[4]; } vld[8];
#pragma unroll
    for (int i = 0; i < 8; ++i)
      vld[i].u = *(const uint2*)(Vbp + (size_t)(kv0 + i * 4 + g) * DD);
    bf16x8 kf[4];
    {
      const bf16* kp = Kb + (size_t)(kv0 + l31) * DD;
#pragma unroll
      for (int kt = 0; kt < 4; ++kt) kf[kt] = *(const bf16x8*)(kp + kt * 16);
    }
    const unsigned mw = mrow[it];
    // stage V^T into private LDS slice: Vl[d][k] (in-wave DS ordering)
#pragma unroll
    for (int i = 0; i < 8; ++i)
#pragma unroll
      for (int j = 0; j < 4; ++j)
        Vl[(l15 * 4 + j) * VKS + i * 4 + g] = vld[i].h4[j];

    // swapped QK^T: S[kv][q], q = l31 per lane
    f32x16 s;
#pragma unroll
    for (int r = 0; r < 16; ++r) s[r] = 0.f;
    __builtin_amdgcn_s_setprio(1);
#pragma unroll
    for (int kt = 0; kt < 4; ++kt) s = mfma32(kf[kt], qf[kt], s);
    __builtin_amdgcn_s_setprio(0);

    float p[16];
#pragma unroll
    for (int r = 0; r < 16; ++r) {
      const int pos = (r & 3) + 8 * (r >> 2) + 4 * hi;
      p[r] = ((mw >> pos) & 1) ? s[r] : -1e9f;
    }
    float rm = p[0];
#pragma unroll
    for (int r = 1; r < 16; ++r) rm = fmaxf(rm, p[r]);
    rm = fmaxf(rm, __shfl_xor(rm, 32));
    if (!__all(rm <= mx + 8.0f)) {            // defer-max (T13)
      const float mn = fmaxf(mx, rm);
      const float scal = fexp2(mx - mn);
      mx = mn; ssum *= scal;
      float sr[16];
#pragma unroll
      for (int r = 0; r < 16; ++r)
        sr[r] = __shfl(scal, (r & 3) + 8 * (r >> 2) + 4 * hi);
#pragma unroll
      for (int dt = 0; dt < 2; ++dt)
#pragma unroll
        for (int r = 0; r < 16; ++r) acco[dt][r] *= sr[r];
    }
#pragma unroll
    for (int r = 0; r < 16; ++r) { p[r] = fexp2(p[r] - mx); ssum += p[r]; }

    // pack to bf16 pairs; dword i = kv pair {K(2i), K(2i)+1} (+4hi)
    int dpk[8];
#pragma unroll
    for (int i = 0; i < 8; ++i) {
      union { bf16 hh[2]; int v; } u;
      u.hh[0] = (bf16)p[2 * i]; u.hh[1] = (bf16)p[2 * i + 1];
      dpk[i] = u.v;
    }
    // XOR-32 exchange: partner holds the other half of each 16-kv k-tile
    const int sa = hi ? dpk[0] : dpk[2], sb = hi ? dpk[1] : dpk[3];
    const int sc_ = hi ? dpk[4] : dpk[6], sd = hi ? dpk[5] : dpk[7];
    const int ra = __shfl_xor(sa, 32), rb = __shfl_xor(sb, 32);
    const int rc = __shfl_xor(sc_, 32), rd = __shfl_xor(sd, 32);
    union { bf16x8 v; int q[4]; } pa0, pa1;
    pa0.q[0] = hi ? ra : dpk[0];  pa0.q[1] = hi ? rb : dpk[1];
    pa0.q[2] = hi ? dpk[2] : ra;  pa0.q[3] = hi ? dpk[3] : rb;
    pa1.q[0] = hi ? rc : dpk[4];  pa1.q[1] = hi ? rd : dpk[5];
    pa1.q[2] = hi ? dpk[6] : rc;  pa1.q[3] = hi ? dpk[7] : rd;

    // PV: O[q][d] += P * V
    __builtin_amdgcn_s_setprio(1);
#pragma unroll
    for (int dt = 0; dt < 2; ++dt) {
      const bf16* vp = &Vl[(dt * 32 + l31) * VKS + 8 * hi];
      bf16x8 v0 = *(const bf16x8*)vp;
      bf16x8 v1 = *(const bf16x8*)(vp + 16);
      acco[dt] = mfma32(pa0.v, v0, acco[dt]);
      acco[dt] = mfma32(pa1.v, v1, acco[dt]);
    }
    __builtin_amdgcn_s_setprio(0);
  }

  // ---- merge 4 kv-quarter partials ----
  ssum += __shfl_xor(ssum, 32);
  __syncthreads();
  if (hi == 0) { sh.m.ml[w][0][l31] = mx; sh.m.ml[w][1][l31] = ssum; }
  __syncthreads();
  if (w == 0 && hi == 0) {
    const float M0 = sh.m.ml[0][0][l31], M1 = sh.m.ml[1][0][l31];
    const float M2 = sh.m.ml[2][0][l31], M3 = sh.m.ml[3][0][l31];
    const float ms = fmaxf(fmaxf(M0, M1), fmaxf(M2, M3));
    const float ls = sh.m.ml[0][1][l31] * fexp2(M0 - ms)
                   + sh.m.ml[1][1][l31] * fexp2(M1 - ms)
                   + sh.m.ml[2][1][l31] * fexp2(M2 - ms)
                   + sh.m.ml[3][1][l31] * fexp2(M3 - ms);
    sh.m.inv[l31] = 1.0f / ls;
    sh.m.mst[l31] = ms;
  }
  __syncthreads();
  float fown[16];
#pragma unroll
  for (int r = 0; r < 16; ++r) {
    const int q_ = (r & 3) + 8 * (r >> 2) + 4 * hi;
    fown[r] = fexp2(sh.m.ml[w][0][q_] - sh.m.mst[q_]);
  }
  for (int rd2 = 0; rd2 < 4; ++rd2) {
    if (w == rd2) {
#pragma unroll
      for (int dt = 0; dt < 2; ++dt)
#pragma unroll
        for (int r = 0; r < 16; ++r) {
          const int q_ = (r & 3) + 8 * (r >> 2) + 4 * hi;
          const int o = q_ * 66 + dt * 32 + l31;
          const float val = acco[dt][r] * fown[r];
          if (rd2 == 0) sh.m.o[o] = val;
          else          sh.m.o[o] += val;
        }
    }
    __syncthreads();
  }
  {
    const int row = tid >> 3, c0 = (tid & 7) * 8;
    const float inv = sh.m.inv[row];
    const float* orow = &sh.m.o[row * 66 + c0];
    bf16x8 ov;
#pragma unroll
    for (int j = 0; j < 8; ++j) ov[j] = (bf16)(orow[j] * inv);
    *(bf16x8*)(Xw + (size_t)(b * SS + q0 + row) * DD + h * 64 + c0) = ov;
  }
}

// ---------------- launch ----------------
extern "C" void kernel_launch(void* const* d_in, const int* in_sizes, int n_in,
                              void* d_out, int out_size, void* d_ws, size_t ws_size,
                              hipStream_t stream) {
  const float* q32 = (const float*)d_in[0];
  const float* k32 = (const float*)d_in[1];
  const float* v32 = (const float*)d_in[2];
  const int* mask = (const int*)d_in[3];
  const float* Wq = (const float*)d_in[4];
  const float* Wk = (const float*)d_in[5];
  const float* Wv = (const float*)d_in[6];
  const float* Wo = (const float*)d_in[7];
  float* out = (float*)d_out;

  const size_t eAct = (size_t)MM * DD;
  const size_t eW = (size_t)DD * DD;

  bf16* Qb = (bf16*)d_ws;
  bf16* Kb = Qb + eAct;
  bf16* Vb = Kb + eAct;
  bf16* Xb = Vb + eAct;
  unsigned* mbits = (unsigned*)(Xb + eAct);
  bf16* cvtBase = (bf16*)(mbits + (size_t)MM * 32);
  bf16* Aq = cvtBase;
  bf16* Ak = Aq + eAct;
  bf16* Av = Ak + eAct;
  bf16* Wqb = Av + eAct;
  bf16* Wkb = Wqb + eW;
  bf16* Wvb = Wkb + eW;
  bf16* Wob = Wvb + eW;
  const size_t need = (size_t)((bf16*)(Wob + eW) - (bf16*)d_ws) * sizeof(bf16);

  k_mask_bits<<<BB * SS, 256, 0, stream>>>(mask, mbits);
  if (ws_size >= need) {
    k_cvt7<<<dim3(2048, 7), 256, 0, stream>>>(q32, k32, v32, Wq, Wk, Wv, Wo,
                                              Aq, Ak, Av, Wqb, Wkb, Wvb, Wob);
    k_gemm_qkv_b16<<<dim3(256, 1, 3), 256, 0, stream>>>(
        Aq, Ak, Av, Wqb, Wkb, Wvb, Qb, Kb, Vb);
    k_attn<<<BB * HH * (SS / 32), 256, 0, stream>>>(Qb, Kb, Vb, mbits, Xb);
    k_gemm_out_b16<<<256, 256, 0, stream>>>(Xb, Wob, out);
  } else {
    k_gemm_qkv<<<dim3((MM / 128) * (DD / 128), 1, 3), 256, 0, stream>>>(
        q32, k32, v32, Wq, Wk, Wv, Qb, Kb, Vb);
    k_attn<<<BB * HH * (SS / 32), 256, 0, stream>>>(Qb, Kb, Vb, mbits, Xb);
    k_gemm_out<<<(MM / 128) * (DD / 128), 256, 0, stream>>>(Xb, Wo, out);
  }
}